// Round 2
// baseline (2161.884 us; speedup 1.0000x reference)
//
#include <hip/hip_runtime.h>
#include <hip/hip_bf16.h>

#define B_ 512
#define T_ 512

__device__ __forceinline__ float sigf(float x) {
    return 1.0f / (1.0f + __expf(-x));
}
__device__ __forceinline__ float tanhfast(float x) {
    // tanh(x) = 1 - 2/(exp(2x)+1); saturates correctly for |x| large
    return 1.0f - 2.0f / (__expf(2.0f * x) + 1.0f);
}

// Persistent per-layer LSTM kernel. ALL I/O fp32 (matches reference dtypes).
//  - grid = 256 blocks, each owns 2 batch rows for all T steps (recurrence is
//    independent across batch; no cross-block sync needed).
//  - thread owns gate row j; combined weight row [Wih[j,:] | Whh[j,:]] lives in
//    VGPRs (K = D+H fp32 regs), reused across all 512 steps.
//  - input vector xcat[r] = [x_t | h_{t-1}] in LDS; broadcast float4 reads
//    (same-address across lanes -> conflict-free broadcast).
//  - RPT==2: NT == 4H, every thread computes its gate for both rows.
//    RPT==1: NT == 2*4H, thread handles one row (r = tid / NJ).
template<int D, int H, int NT, int RPT, bool LAST>
__global__ __launch_bounds__(NT)
void lstm_layer(const float* __restrict__ xin,   // [B,T,D]
                const float* __restrict__ Wih,   // [4H,D]
                const float* __restrict__ Whh,   // [4H,H]
                const float* __restrict__ bih,   // [4H]
                const float* __restrict__ bhh,   // [4H]
                float* __restrict__ yout,        // [B,T,H]
                float* __restrict__ hn)          // [B,H] (LAST only)
{
    constexpr int NJ = 4 * H;
    constexpr int K  = D + H;
    constexpr int K4 = K / 4;
    static_assert(K % 4 == 0, "K must be multiple of 4");

    const int tid = threadIdx.x;
    const int b0  = blockIdx.x * 2;
    const int j   = (RPT == 2) ? tid : (tid % NJ);

    // ---- load combined weight row into registers (reused 512 steps) ----
    float W[K];
#pragma unroll
    for (int k = 0; k < D; ++k) W[k]     = Wih[j * D + k];
#pragma unroll
    for (int k = 0; k < H; ++k) W[D + k] = Whh[j * H + k];
    const float bj = bih[j] + bhh[j];

    __shared__ float xcat[2][K];    // [row][ x(0:D) | h(D:D+H) ]
    __shared__ float graw[2][NJ];   // raw gate pre-activations

    // ---- init: h0 = 0, stage x_0 ----
    for (int i = tid; i < 2 * H; i += NT) xcat[i / H][D + (i % H)] = 0.0f;
    for (int i = tid; i < 2 * D; i += NT) {
        const int r = i / D, d = i % D;
        xcat[r][d] = xin[((size_t)(b0 + r) * T_ + 0) * D + d];
    }
    float c = 0.0f;                 // cell state (valid for tid < 2H)
    __syncthreads();

    const int ur = tid / H;         // update role: row   (tid < 2H)
    const int um = tid % H;         // update role: unit
    const int pr = tid / D;         // prefetch role: row (tid < 2D)
    const int pd = tid % D;         // prefetch role: feat

    for (int t = 0; t < T_; ++t) {
        // ---- prefetch x_{t+1} into a register (hidden under compute) ----
        float xn = 0.0f;
        const bool pref = (t + 1 < T_) && (tid < 2 * D);
        if (pref) {
            xn = xin[((size_t)(b0 + pr) * T_ + (t + 1)) * D + pd];
        }

        // ---- gate pre-activation: g = bj + W . xcat[row] ----
        if (RPT == 2) {
            const float4* x0 = (const float4*)(&xcat[0][0]);
            const float4* x1 = (const float4*)(&xcat[1][0]);
            float s0[2] = {bj, 0.0f};
            float s1[2] = {bj, 0.0f};
#pragma unroll
            for (int k4 = 0; k4 < K4; ++k4) {
                const float4 u0 = x0[k4];
                const float4 u1 = x1[k4];
                const int a = k4 & 1;
                s0[a] = fmaf(W[4 * k4 + 0], u0.x, s0[a]);
                s0[a] = fmaf(W[4 * k4 + 1], u0.y, s0[a]);
                s0[a] = fmaf(W[4 * k4 + 2], u0.z, s0[a]);
                s0[a] = fmaf(W[4 * k4 + 3], u0.w, s0[a]);
                s1[a] = fmaf(W[4 * k4 + 0], u1.x, s1[a]);
                s1[a] = fmaf(W[4 * k4 + 1], u1.y, s1[a]);
                s1[a] = fmaf(W[4 * k4 + 2], u1.z, s1[a]);
                s1[a] = fmaf(W[4 * k4 + 3], u1.w, s1[a]);
            }
            graw[0][j] = s0[0] + s0[1];
            graw[1][j] = s1[0] + s1[1];
        } else {
            const int r = tid / NJ;
            const float4* xr = (const float4*)(&xcat[r][0]);
            float s[2] = {bj, 0.0f};
#pragma unroll
            for (int k4 = 0; k4 < K4; ++k4) {
                const float4 u = xr[k4];
                const int a = k4 & 1;
                s[a] = fmaf(W[4 * k4 + 0], u.x, s[a]);
                s[a] = fmaf(W[4 * k4 + 1], u.y, s[a]);
                s[a] = fmaf(W[4 * k4 + 2], u.z, s[a]);
                s[a] = fmaf(W[4 * k4 + 3], u.w, s[a]);
            }
            graw[r][j] = s[0] + s[1];
        }
        __syncthreads();

        // ---- gate nonlinearity + state update (threads 0 .. 2H-1) ----
        if (tid < 2 * H) {
            const float gi = sigf(graw[ur][um]);
            const float gf = sigf(graw[ur][H + um]);
            const float gg = tanhfast(graw[ur][2 * H + um]);
            const float go = sigf(graw[ur][3 * H + um]);
            c = gf * c + gi * gg;
            const float h = go * tanhfast(c);
            xcat[ur][D + um] = h;   // feed next step
            yout[((size_t)(b0 + ur) * T_ + t) * H + um] = h;
            if (LAST && t == T_ - 1) hn[(b0 + ur) * H + um] = h;
        }
        if (pref) xcat[pr][pd] = xn;  // stage x_{t+1}
        __syncthreads();
    }
}

extern "C" void kernel_launch(void* const* d_in, const int* in_sizes, int n_in,
                              void* d_out, int out_size, void* d_ws, size_t ws_size,
                              hipStream_t stream)
{
    const float* z    = (const float*)d_in[0];
    const float* Wih1 = (const float*)d_in[1];
    const float* Whh1 = (const float*)d_in[2];
    const float* bih1 = (const float*)d_in[3];
    const float* bhh1 = (const float*)d_in[4];
    const float* Wih2 = (const float*)d_in[5];
    const float* Whh2 = (const float*)d_in[6];
    const float* bih2 = (const float*)d_in[7];
    const float* bhh2 = (const float*)d_in[8];
    const float* Wih3 = (const float*)d_in[9];
    const float* Whh3 = (const float*)d_in[10];
    const float* bih3 = (const float*)d_in[11];
    const float* bhh3 = (const float*)d_in[12];

    // workspace: inter-layer activations (fp32)
    float* h1 = (float*)d_ws;                                        // [B,T,32]  33.5 MB
    float* h2 = (float*)((char*)d_ws + (size_t)B_ * T_ * 32 * 4);    // [B,T,48]  50.3 MB

    float* out = (float*)d_out;                                      // [B,T,128]
    float* hn  = out + (size_t)B_ * T_ * 128;                        // [1,B,128]

    // layer 1: D=64  H=32  -> NT=256 (j x 2 rows), K=96
    hipLaunchKernelGGL((lstm_layer<64, 32, 256, 1, false>),
                       dim3(256), dim3(256), 0, stream,
                       z, Wih1, Whh1, bih1, bhh1, h1, (float*)nullptr);
    // layer 2: D=32  H=48  -> NT=384 (j x 2 rows), K=80
    hipLaunchKernelGGL((lstm_layer<32, 48, 384, 1, false>),
                       dim3(256), dim3(384), 0, stream,
                       h1, Wih2, Whh2, bih2, bhh2, h2, (float*)nullptr);
    // layer 3: D=48  H=128 -> NT=512 (one j per thread, 2 rows each), K=176
    hipLaunchKernelGGL((lstm_layer<48, 128, 512, 2, true>),
                       dim3(256), dim3(512), 0, stream,
                       h2, Wih3, Whh3, bih3, bhh3, out, hn);
}

// Round 3
// 1630.546 us; speedup vs baseline: 1.3259x; 1.3259x over previous
//
#include <hip/hip_runtime.h>
#include <hip/hip_bf16.h>

#define B_ 512
#define T_ 512

typedef __bf16 bf16x8 __attribute__((ext_vector_type(8)));
typedef float  f32x4  __attribute__((ext_vector_type(4)));
using u16 = unsigned short;

__device__ __forceinline__ float fast_rcp(float x) { return __builtin_amdgcn_rcpf(x); }
__device__ __forceinline__ float sigf(float x)     { return fast_rcp(1.0f + __expf(-x)); }
__device__ __forceinline__ float tanhfast(float x) { return 1.0f - 2.0f * fast_rcp(__expf(2.0f * x) + 1.0f); }

// fp32 -> bf16 RNE
__device__ __forceinline__ u16 f2bf(float f) {
    unsigned u = __float_as_uint(f);
    u += 0x7FFFu + ((u >> 16) & 1u);
    return (u16)(u >> 16);
}

// Persistent MFMA LSTM layer. 32 blocks x 16 batch rows, T-loop inside.
// Weights live in registers as MFMA B-fragments (cols reordered n = 4*u + gate
// so a unit's 4 gates share a 4-lane group -> shuffle transpose, no LDS for
// gates; c-state stays in-lane). xcat = [x_t | h_{t-1}] bf16 in LDS, double
// buffered -> ONE barrier/step so LDS/MFMA/VALU phases overlap across waves.
template<int D, int H, int WAVES, int TPW, bool IN_BF16, bool OUT_BF16, bool LAST>
__global__ __launch_bounds__(WAVES * 64)
void lstm_mfma(const void* __restrict__ xin,
               const float* __restrict__ Wih, const float* __restrict__ Whh,
               const float* __restrict__ bih, const float* __restrict__ bhh,
               void* __restrict__ yout, float* __restrict__ hn)
{
    constexpr int K    = D + H;
    constexpr int KF   = (K + 31) / 32;       // K-fragments (pad to 32)
    constexpr int KPAD = KF * 32;
    constexpr int SSTR = KPAD + 8;            // LDS row stride (bf16): +8 -> 2-way bank alias (free)
    constexpr int NT   = WAVES * 64;
    constexpr int NTILE = TPW * WAVES;        // N-tiles of 16 = 4H/16
    static_assert(NTILE * 16 == 4 * H, "tile cover");
    constexpr int XW   = 16 * D / 2;          // dwords of x staged per step
    static_assert(XW <= NT, "one staging load per thread");

    const int tid  = threadIdx.x;
    const int lane = tid & 63;
    const int wv   = tid >> 6;
    const int q    = lane >> 4;               // quad
    const int cc   = lane & 15;               // col within 16-wide tile
    const int b0   = blockIdx.x * 16;

    __shared__ u16 xcat[2][16 * SSTR];

    // ---- B-fragments (weights, gate-interleaved), bias, c-state ----
    bf16x8 WB[TPW][KF];
    float  bias[TPW][4];
    float  cst[TPW];
#pragma unroll
    for (int tp = 0; tp < TPW; ++tp) {
        const int nglob = (wv * TPW + tp) * 16 + cc;   // reordered col
        const int u = nglob >> 2, g = nglob & 3;
        const int row = g * H + u;                     // original 4H row (i,f,g,o blocks)
#pragma unroll
        for (int kf = 0; kf < KF; ++kf) {
            bf16x8 w;
#pragma unroll
            for (int j = 0; j < 8; ++j) {
                const int k = kf * 32 + q * 8 + j;
                float v = 0.0f;
                if (k < D)      v = Wih[row * D + k];
                else if (k < K) v = Whh[row * H + (k - D)];
                w[j] = (__bf16)v;
            }
            WB[tp][kf] = w;
        }
        const int uu = (wv * TPW + tp) * 4 + (cc >> 2);  // unit this lane updates
#pragma unroll
        for (int g2 = 0; g2 < 4; ++g2)
            bias[tp][g2] = bih[g2 * H + uu] + bhh[g2 * H + uu];
        cst[tp] = 0.0f;
    }

    // ---- init LDS (zeros incl. K-padding), stage x_0 into buf 0 ----
    for (int i = tid; i < 2 * 16 * SSTR; i += NT) (&xcat[0][0])[i] = 0;
    __syncthreads();
    const int xr = tid / (D / 2);             // staging row
    const int xp = tid % (D / 2);             // staging dword within row
    if (tid < XW) {
        unsigned pk;
        const size_t gi = ((size_t)(b0 + xr) * T_ + 0) * (D / 2) + xp;
        if constexpr (IN_BF16) {
            pk = ((const unsigned*)xin)[gi];
        } else {
            const float2 f = ((const float2*)xin)[gi];
            pk = (unsigned)f2bf(f.x) | ((unsigned)f2bf(f.y) << 16);
        }
        *(unsigned*)&xcat[0][xr * SSTR + 2 * xp] = pk;
    }
    __syncthreads();

    const f32x4 zed = {0.0f, 0.0f, 0.0f, 0.0f};
    const int  rr = 4 * q + (lane & 3);       // row this lane updates (post-transpose)
    const bool bA = lane & 1, bB = lane & 2;

    for (int t = 0; t < T_; ++t) {
        const int cur = t & 1, nxt = cur ^ 1;

        // ---- A-fragments for step t: A[m=cc][k=kf*32+q*8+j] ----
        bf16x8 A[KF];
#pragma unroll
        for (int kf = 0; kf < KF; ++kf)
            A[kf] = *(const bf16x8*)&xcat[cur][cc * SSTR + kf * 32 + q * 8];

        // ---- prefetch x_{t+1} from global (latency hides under MFMA) ----
        unsigned pk = 0;
        const bool hasx = (t + 1 < T_) && (tid < XW);
        if (hasx) {
            const size_t gi = ((size_t)(b0 + xr) * T_ + (t + 1)) * (D / 2) + xp;
            if constexpr (IN_BF16) {
                pk = ((const unsigned*)xin)[gi];
            } else {
                const float2 f = ((const float2*)xin)[gi];
                pk = (unsigned)f2bf(f.x) | ((unsigned)f2bf(f.y) << 16);
            }
        }

        // ---- MFMA: preact[16 x 4H] = xcat @ Wr^T ----
        f32x4 acc[TPW];
#pragma unroll
        for (int tp = 0; tp < TPW; ++tp) acc[tp] = zed;
#pragma unroll
        for (int kf = 0; kf < KF; ++kf)
#pragma unroll
            for (int tp = 0; tp < TPW; ++tp)
                acc[tp] = __builtin_amdgcn_mfma_f32_16x16x32_bf16(A[kf], WB[tp][kf], acc[tp], 0, 0, 0);

        // ---- 4x4 lane-group transpose -> lane holds (i,f,g,o) for its (rr,u) ----
#pragma unroll
        for (int tp = 0; tp < TPW; ++tp) {
            float v0 = acc[tp][0], v1 = acc[tp][1], v2 = acc[tp][2], v3 = acc[tp][3];
            float s;
            s = __shfl_xor(bA ? v0 : v1, 1); if (bA) v0 = s; else v1 = s;
            s = __shfl_xor(bA ? v2 : v3, 1); if (bA) v2 = s; else v3 = s;
            s = __shfl_xor(bB ? v0 : v2, 2); if (bB) v0 = s; else v2 = s;
            s = __shfl_xor(bB ? v1 : v3, 2); if (bB) v1 = s; else v3 = s;

            const float gi = sigf(v0 + bias[tp][0]);
            const float gf = sigf(v1 + bias[tp][1]);
            const float gg = tanhfast(v2 + bias[tp][2]);
            const float go = sigf(v3 + bias[tp][3]);
            const float c  = gf * cst[tp] + gi * gg;
            cst[tp] = c;
            const float h  = go * tanhfast(c);

            const int u = (wv * TPW + tp) * 4 + (cc >> 2);
            xcat[nxt][rr * SSTR + D + u] = f2bf(h);          // feed step t+1
            const size_t oi = ((size_t)(b0 + rr) * T_ + t) * H + u;
            if constexpr (OUT_BF16) ((u16*)yout)[oi] = f2bf(h);
            else                    ((float*)yout)[oi] = h;
            if (LAST && t == T_ - 1) hn[(b0 + rr) * H + u] = h;
        }

        // ---- stage x_{t+1} into next buffer ----
        if (hasx) *(unsigned*)&xcat[nxt][xr * SSTR + 2 * xp] = pk;

        __syncthreads();   // one barrier: buf[nxt] writes done / buf[cur] reads done
    }
}

extern "C" void kernel_launch(void* const* d_in, const int* in_sizes, int n_in,
                              void* d_out, int out_size, void* d_ws, size_t ws_size,
                              hipStream_t stream)
{
    (void)in_sizes; (void)n_in; (void)out_size; (void)ws_size;
    const float* z    = (const float*)d_in[0];
    const float* Wih1 = (const float*)d_in[1];
    const float* Whh1 = (const float*)d_in[2];
    const float* bih1 = (const float*)d_in[3];
    const float* bhh1 = (const float*)d_in[4];
    const float* Wih2 = (const float*)d_in[5];
    const float* Whh2 = (const float*)d_in[6];
    const float* bih2 = (const float*)d_in[7];
    const float* bhh2 = (const float*)d_in[8];
    const float* Wih3 = (const float*)d_in[9];
    const float* Whh3 = (const float*)d_in[10];
    const float* bih3 = (const float*)d_in[11];
    const float* bhh3 = (const float*)d_in[12];

    // inter-layer activations in bf16 (they feed the next layer's MFMA A-operand)
    u16* h1 = (u16*)d_ws;                                     // [B,T,32] bf16, 16.8 MB
    u16* h2 = (u16*)((char*)d_ws + (size_t)B_ * T_ * 32 * 2); // [B,T,48] bf16, 25.2 MB

    float* out = (float*)d_out;                               // [B,T,128] fp32
    float* hn  = out + (size_t)B_ * T_ * 128;                 // [1,B,128] fp32

    // L1: D=64 H=32  (8 N-tiles)  8 waves x 1 tile
    hipLaunchKernelGGL((lstm_mfma<64, 32, 8, 1, false, true, false>),
                       dim3(32), dim3(512), 0, stream,
                       (const void*)z, Wih1, Whh1, bih1, bhh1, (void*)h1, (float*)nullptr);
    // L2: D=32 H=48  (12 N-tiles) 6 waves x 2 tiles
    hipLaunchKernelGGL((lstm_mfma<32, 48, 6, 2, true, true, false>),
                       dim3(32), dim3(384), 0, stream,
                       (const void*)h1, Wih2, Whh2, bih2, bhh2, (void*)h2, (float*)nullptr);
    // L3: D=48 H=128 (32 N-tiles) 8 waves x 4 tiles
    hipLaunchKernelGGL((lstm_mfma<48, 128, 8, 4, true, false, true>),
                       dim3(32), dim3(512), 0, stream,
                       (const void*)h2, Wih3, Whh3, bih3, bhh3, (void*)out, hn);
}